// Round 2
// baseline (671.851 us; speedup 1.0000x reference)
//
#include <hip/hip_runtime.h>
#include <math.h>

#define NH 16
#define HD 128
#define SD 64
#define SLOTS 16
#define DIM 2048
#define NEGV -1e9f

// one block per token; 256 threads = 4 waves; wave w owns heads 4w..4w+3; lane = sd
__global__ __launch_bounds__(256, 2) void stackmem_kernel(
    const float* __restrict__ hid,       // [T, DIM]
    const float* __restrict__ stack_in,  // [T, NH, SLOTS, SD]
    const float* __restrict__ mask_in,   // [T, NH, SLOTS]
    const float* __restrict__ Wa,        // [48, DIM]
    const float* __restrict__ Wg,        // [SD]
    const float* __restrict__ Wd,        // [SD, HD]
    const float* __restrict__ Wu,        // [HD, SD]
    const float* __restrict__ resw,      // [1]
    float* __restrict__ out,             // [T, DIM]
    float* __restrict__ stack_out,       // [T, NH, SLOTS, SD]
    float* __restrict__ mask_out)        // [T, NH, SLOTS]
{
    __shared__ __align__(16) float hid_s[DIM];        // 8 KB
    __shared__ __align__(16) float wdT[HD * SD];      // 32 KB: wdT[hd*64+sd] = Wd[sd][hd]
    __shared__ __align__(16) float wuT[SD * HD];      // 32 KB: wuT[sd*128+hd] = Wu[hd][sd]
    __shared__ float msk_s[NH * SLOTS];               // 1 KB
    __shared__ float mo_s[NH * SD];                   // 4 KB

    const int t   = blockIdx.x;
    const int tid = threadIdx.x;
    const int w   = tid >> 6;   // wave id
    const int l   = tid & 63;   // lane id == sd

    // ---- Phase 0: stage shared data ----
    {
        const float4* h4 = (const float4*)(hid + (size_t)t * DIM);
        float4* s4 = (float4*)hid_s;
        #pragma unroll
        for (int i = 0; i < DIM / 4 / 256; ++i) s4[tid + i * 256] = h4[tid + i * 256];
    }
    msk_s[tid] = mask_in[(size_t)t * NH * SLOTS + tid];  // 256 == NH*SLOTS
    for (int i = tid; i < HD * SD; i += 256) {
        int hd_ = i >> 6, sd_ = i & 63;
        wdT[i] = Wd[sd_ * HD + hd_];
    }
    for (int i = tid; i < SD * HD; i += 256) {
        int sd_ = i >> 7, hd_ = i & 127;
        wuT[i] = Wu[hd_ * SD + sd_];
    }
    __syncthreads();

    // ---- Phase 1: action logits (wave w -> logits 12w..12w+11) ----
    float lg[12];
    {
        const float4* hs4 = (const float4*)hid_s;
        for (int jj = 0; jj < 12; ++jj) {
            const int j = 12 * w + jj;
            const float4* wa4 = (const float4*)(Wa + (size_t)j * DIM);
            float acc = 0.f;
            #pragma unroll
            for (int it = 0; it < 8; ++it) {
                int d4 = it * 64 + l;
                float4 a = wa4[d4];
                float4 b = hs4[d4];
                acc += a.x * b.x + a.y * b.y + a.z * b.z + a.w * b.w;
            }
            #pragma unroll
            for (int off = 32; off; off >>= 1) acc += __shfl_xor(acc, off, 64);
            lg[jj] = acc * 0.08838834764831845f;  // 1/sqrt(128)
        }
    }
    float a_push[4], a_pop[4], a_noop[4];
    #pragma unroll
    for (int q = 0; q < 4; ++q) {
        float l0 = lg[3 * q], l1 = lg[3 * q + 1], l2 = lg[3 * q + 2];
        float m  = fmaxf(l0, fmaxf(l1, l2));
        float e0 = __expf(l0 - m), e1 = __expf(l1 - m), e2 = __expf(l2 - m);
        float inv = 1.f / (e0 + e1 + e2);
        a_push[q] = e0 * inv; a_pop[q] = e1 * inv; a_noop[q] = e2 * inv;
    }

    // ---- Phase 2: k = per-head down-proj; k[h][sd=l] ----
    float kacc[4] = {0.f, 0.f, 0.f, 0.f};
    {
        const int hbase = w * 4 * HD;
        #pragma unroll 2
        for (int hd4 = 0; hd4 < HD; hd4 += 4) {
            float w0 = wdT[(hd4 + 0) * 64 + l];
            float w1 = wdT[(hd4 + 1) * 64 + l];
            float w2 = wdT[(hd4 + 2) * 64 + l];
            float w3 = wdT[(hd4 + 3) * 64 + l];
            #pragma unroll
            for (int q = 0; q < 4; ++q) {
                float4 hv = *(const float4*)&hid_s[hbase + q * HD + hd4];
                kacc[q] += hv.x * w0 + hv.y * w1 + hv.z * w2 + hv.w * w3;
            }
        }
    }

    // ---- Phase 3: stack update + gating per head ----
    const float res_w = resw[0];
    const float wg = Wg[l];
    for (int q = 0; q < 4; ++q) {
        const int h = 4 * w + q;
        const float* strow = stack_in + ((size_t)t * NH + h) * (SLOTS * SD);
        float st[SLOTS];
        #pragma unroll
        for (int i = 0; i < SLOTS; ++i) st[i] = strow[i * SD + l];
        float mk[SLOTS];
        #pragma unroll
        for (int i = 0; i < SLOTS; ++i) mk[i] = msk_s[h * SLOTS + i];  // broadcast

        const float ap = a_push[q], ao = a_pop[q], an = a_noop[q];
        float ns[SLOTS], nm[SLOTS];
        #pragma unroll
        for (int i = 0; i < SLOTS; ++i) {
            float ps = (i == 0) ? kacc[q] : st[i - 1];
            float pm = (i == 0) ? 1.f : mk[i - 1];
            float os = (i < SLOTS - 1) ? st[i + 1] : 0.f;
            float om = (i < SLOTS - 1) ? mk[i + 1] : 0.f;
            ns[i] = ap * ps + ao * os + an * st[i];
            nm[i] = ap * pm + ao * om + an * mk[i];
        }
        // write new_stack (coalesced 256B rows)
        float* so = stack_out + ((size_t)t * NH + h) * (SLOTS * SD);
        #pragma unroll
        for (int i = 0; i < SLOTS; ++i) so[i * SD + l] = ns[i];
        // write new_mask
        if (l < SLOTS) mask_out[((size_t)t * NH + h) * SLOTS + l] = nm[l];

        // gate scores: 16 cross-lane dot products with W_gate
        float sc[SLOTS];
        #pragma unroll
        for (int i = 0; i < SLOTS; ++i) {
            float v = ns[i] * wg;
            #pragma unroll
            for (int off = 32; off; off >>= 1) v += __shfl_xor(v, off, 64);
            sc[i] = v;
        }
        // masked softmax over slots (every lane computes it; comm-free)
        float m = -INFINITY;
        #pragma unroll
        for (int i = 0; i < SLOTS; ++i) {
            sc[i] += (1.f - nm[i]) * NEGV;
            m = fmaxf(m, sc[i]);
        }
        float ssum = 0.f;
        #pragma unroll
        for (int i = 0; i < SLOTS; ++i) { sc[i] = __expf(sc[i] - m); ssum += sc[i]; }
        const float inv = 1.f / ssum;
        float acc = 0.f;
        #pragma unroll
        for (int i = 0; i < SLOTS; ++i) acc += sc[i] * ns[i];
        mo_s[h * SD + l] = acc * inv;   // memory_output[h][sd=l]
    }
    __syncthreads();

    // ---- Phase 4: up-proj + residual; batch 4 heads per wuT read ----
    {
        float o[4][2] = {};
        #pragma unroll 4
        for (int sd = 0; sd < SD; ++sd) {
            float u0 = wuT[sd * HD + l];
            float u1 = wuT[sd * HD + l + 64];
            #pragma unroll
            for (int q = 0; q < 4; ++q) {
                float mv = mo_s[(4 * w + q) * SD + sd];  // broadcast
                o[q][0] += mv * u0;
                o[q][1] += mv * u1;
            }
        }
        float* orow = out + (size_t)t * DIM;
        #pragma unroll
        for (int q = 0; q < 4; ++q) {
            const int h = 4 * w + q;
            orow[h * HD + l]      = o[q][0] * res_w + hid_s[h * HD + l];
            orow[h * HD + l + 64] = o[q][1] * res_w + hid_s[h * HD + l + 64];
        }
    }
}

extern "C" void kernel_launch(void* const* d_in, const int* in_sizes, int n_in,
                              void* d_out, int out_size, void* d_ws, size_t ws_size,
                              hipStream_t stream) {
    const float* hid      = (const float*)d_in[0];
    const float* stack_in = (const float*)d_in[1];
    const float* mask_in  = (const float*)d_in[2];
    const float* Wa       = (const float*)d_in[3];
    const float* Wg       = (const float*)d_in[4];
    const float* Wd       = (const float*)d_in[5];
    const float* Wu       = (const float*)d_in[6];
    const float* resw     = (const float*)d_in[7];

    const int T = in_sizes[0] / DIM;  // B*S = 4096

    float* out_p      = (float*)d_out;
    float* stack_out  = out_p + (size_t)T * DIM;
    float* mask_out   = stack_out + (size_t)T * NH * SLOTS * SD;

    dim3 grid(T), block(256);
    hipLaunchKernelGGL(stackmem_kernel, grid, block, 0, stream,
                       hid, stack_in, mask_in, Wa, Wg, Wd, Wu, resw,
                       out_p, stack_out, mask_out);
}